// Round 11
// baseline (74.711 us; speedup 1.0000x reference)
//
#include <hip/hip_runtime.h>
#include <hip/hip_bf16.h>
#include <stdint.h>

#define NROWS 4096
#define DIMS  2048
#define BMI   128             // tile rows (bi dim)
#define BNJ   256             // tile cols (bj dim)
#define BKB   64              // K-tile = 64 int8 bytes per row
#define NTILES (DIMS / BKB)   // 32
#define NTBI  (NROWS / BMI)   // 32
#define NTBJ  (NROWS / BNJ)   // 16 -> grid 512 = 2 blocks/CU
#define MARGIN_F 0.3f

typedef __attribute__((ext_vector_type(4))) int   i32x4;
typedef __attribute__((ext_vector_type(4))) float f32x4;

__device__ inline void atomicMaxF(float* addr, float v) {
  if (v >= 0.f) atomicMax((int*)addr, __float_as_int(v));
  else          atomicMin((unsigned int*)addr, __float_as_uint(v));
}
__device__ inline void atomicMinF(float* addr, float v) {
  if (v >= 0.f) atomicMin((int*)addr, __float_as_int(v));
  else          atomicMax((unsigned int*)addr, __float_as_uint(v));
}

__device__ inline void load_lds16(const void* g, void* l) {
  __builtin_amdgcn_global_load_lds(
      (const __attribute__((address_space(1))) void*)(g),
      (__attribute__((address_space(3))) void*)(l), 16, 0, 0);
}

// ------- normalize + per-row int8 quantization (q = rint(x*127/amax)) -------
__global__ __launch_bounds__(256) void norm_kernel(const float* __restrict__ in,
                                                   char* __restrict__ l2q,
                                                   float* __restrict__ recip,
                                                   float* __restrict__ dap,
                                                   float* __restrict__ dan) {
  int row = blockIdx.x;
  int t = threadIdx.x;
  const float4* rin = (const float4*)(in + (size_t)row * DIMS);
  float4 v0 = rin[t];
  float4 v1 = rin[t + 256];
  float ss = v0.x*v0.x + v0.y*v0.y + v0.z*v0.z + v0.w*v0.w
           + v1.x*v1.x + v1.y*v1.y + v1.z*v1.z + v1.w*v1.w;
  float am = fmaxf(fmaxf(fmaxf(fabsf(v0.x), fabsf(v0.y)), fmaxf(fabsf(v0.z), fabsf(v0.w))),
                   fmaxf(fmaxf(fabsf(v1.x), fabsf(v1.y)), fmaxf(fabsf(v1.z), fabsf(v1.w))));
  #pragma unroll
  for (int s = 1; s < 64; s <<= 1) {
    ss += __shfl_xor(ss, s);
    am = fmaxf(am, __shfl_xor(am, s));
  }
  __shared__ float wsum[4], wmax[4];
  if ((t & 63) == 0) { wsum[t >> 6] = ss; wmax[t >> 6] = am; }
  __syncthreads();
  float tot = wsum[0] + wsum[1] + wsum[2] + wsum[3];
  float amax = fmaxf(fmaxf(wmax[0], wmax[1]), fmaxf(wmax[2], wmax[3]));
  float rn = 1.0f / sqrtf(tot);
  float qs = 127.0f / amax;
  int q0 = (int)rintf(v0.x * qs), q1 = (int)rintf(v0.y * qs);
  int q2 = (int)rintf(v0.z * qs), q3 = (int)rintf(v0.w * qs);
  int q4 = (int)rintf(v1.x * qs), q5 = (int)rintf(v1.y * qs);
  int q6 = (int)rintf(v1.z * qs), q7 = (int)rintf(v1.w * qs);
  int p0 = (q0 & 255) | ((q1 & 255) << 8) | ((q2 & 255) << 16) | (q3 << 24);
  int p1 = (q4 & 255) | ((q5 & 255) << 8) | ((q6 & 255) << 16) | (q7 << 24);
  int* orow = (int*)(l2q + (size_t)row * DIMS);
  orow[t] = p0;
  orow[t + 256] = p1;
  if (t == 0) {
    recip[row] = amax * rn / 127.0f;
    dap[row] = -__builtin_inff();
    dan[row] = __builtin_inff();
  }
}

// ---------------- fused int8 GEMM (acc = Q . Q^T) + masked row max/min ----------------
// 128x256 tile, 4 waves (1M x 4N, wave tile 128x64), BK=64 int8,
// mfma_i32_16x16x64_i8 (32 MFMA/wave/K-tile over 2 phases of 16).
// GRID 512 = 2 INDEPENDENT blocks/CU (72 KB LDS, ~200 VGPR -> 2 waves/SIMD
// from DIFFERENT blocks): when one block stalls at its barrier/gate, the
// other block's waves feed the MFMA/LDS pipes (m114 overlap) -- attacks the
// lockstep phase serialization that capped r5-r10 at ~33% MfmaUtil.
// LDS: 3 sets x (A[128][64] 8KB + B[256][64] 16KB) = 72 KB; stage tile t+2
// while computing t (prefetch ~2 tile-times); gate vmcnt(10) at P1 drains
// exactly tile t's 6 loads. P2 does lgkmcnt(0) BEFORE its barrier so all
// reads of set t%3 are in registers before any next-tile overwrite issues.
// Chunk swizzle q = c ^ ((row>>1)&3) within each 64B row -- byte-identical
// to r4-r10's verified zero-conflict granule; staging = linear LDS dest +
// pre-swizzled coalesced global source.
__global__ __launch_bounds__(256, 2) void gemm_reduce_kernel(
    const char* __restrict__ l2q, const int* __restrict__ tgt,
    const float* __restrict__ recip,
    float* __restrict__ dap, float* __restrict__ dan) {
  __shared__ __attribute__((aligned(16))) char ldsbuf[73728];  // 3 sets x 24 KB

  // XCD-chunked bijective swizzle (512 blocks, 8 XCDs -> 64 contiguous per XCD)
  int c = blockIdx.x;
  int swz = (c & 7) * 64 + (c >> 3);
  int bi = swz >> 4, bj = swz & 15;   // bi 0..31, bj 0..15

  int tid = threadIdx.x;
  int lane = tid & 63, w = tid >> 6;  // w = 0..3: N quarter (64 cols)

  i32x4 acc[8][4];
  #pragma unroll
  for (int m = 0; m < 8; m++)
    #pragma unroll
    for (int n = 0; n < 4; n++) acc[m][n] = (i32x4){0, 0, 0, 0};

  // --- staging source: slot s -> row s>>2, chunk-slot s&3 holds data chunk
  //     q = (s&3) ^ ((row>>1)&3); thread t covers slots t + j*256 (same q) ---
  int srow = tid >> 2;                               // 0..63
  int qq = (tid & 3) ^ ((tid >> 3) & 3);
  const char* gA = l2q + ((size_t)(bi * BMI + srow)) * DIMS + qq * 16;
  const char* gB = l2q + ((size_t)(bj * BNJ + srow)) * DIMS + qq * 16;

  // --- fragment read offsets (bytes within a set) ---
  int laneq = lane & 15, g = lane >> 4;
  int fc = (g ^ ((laneq >> 1) & 3)) * 16;            // swizzled 16B chunk slot
  int aOffB = laneq * 64 + fc;                        // + m*1024
  int bOffB = 8192 + (w * 64 + laneq) * 64 + fc;      // + n*1024

  i32x4 aU[4], aV[4], bR[4];

  // set byte offsets: SET(k) = k*24576; A at +0 (8KB), B at +8192 (16KB)
  #define STAGE_A(T, D)                                                       \
    do {                                                                      \
      load_lds16(gA + (size_t)(T) * 64,              &ldsbuf[(D) + w * 1024]); \
      load_lds16(gA + (size_t)64 * DIMS + (size_t)(T) * 64,                   \
                 &ldsbuf[(D) + 4096 + w * 1024]);                             \
    } while (0)
  #define STAGE_BH0(T, D)                                                     \
    do {                                                                      \
      load_lds16(gB + (size_t)(T) * 64,              &ldsbuf[(D) + 8192 + w * 1024]); \
      load_lds16(gB + (size_t)64 * DIMS + (size_t)(T) * 64,                   \
                 &ldsbuf[(D) + 12288 + w * 1024]);                            \
    } while (0)
  #define STAGE_BH1(T, D)                                                     \
    do {                                                                      \
      load_lds16(gB + (size_t)128 * DIMS + (size_t)(T) * 64,                  \
                 &ldsbuf[(D) + 16384 + w * 1024]);                            \
      load_lds16(gB + (size_t)192 * DIMS + (size_t)(T) * 64,                  \
                 &ldsbuf[(D) + 20480 + w * 1024]);                            \
    } while (0)

  #define READ_A4(DST, MB, CUR)                                               \
    _Pragma("unroll")                                                         \
    for (int m = 0; m < 4; m++)                                               \
      DST[m] = *(const i32x4*)&ldsbuf[(CUR) + aOffB + ((MB) + m) * 1024];
  #define READ_B4(DST, CUR)                                                   \
    _Pragma("unroll")                                                         \
    for (int n = 0; n < 4; n++)                                               \
      DST[n] = *(const i32x4*)&ldsbuf[(CUR) + bOffB + n * 1024];

  #define MFMA16(MB, AR, BR)                                                  \
    __builtin_amdgcn_s_setprio(1);                                            \
    _Pragma("unroll")                                                         \
    for (int m = 0; m < 4; m++)                                               \
      _Pragma("unroll")                                                       \
      for (int n = 0; n < 4; n++)                                             \
        acc[(MB) + m][n] = __builtin_amdgcn_mfma_i32_16x16x64_i8(             \
            AR[m], BR[n], acc[(MB) + m][n], 0, 0, 0);                         \
    __builtin_amdgcn_s_setprio(0);

  #define SB __builtin_amdgcn_sched_barrier(0);
  #define LGKM0 asm volatile("s_waitcnt lgkmcnt(0)" ::: "memory"); SB
  #define VM10  asm volatile("s_waitcnt vmcnt(10)" ::: "memory"); SB
  #define BAR   __builtin_amdgcn_s_barrier(); SB

  // ITER(tile set CUR, stage dest DST, stage tile TN):
  //  P1: reads (data staged 2 tiles ago, safe-by-distance); stage A+Bh0 of
  //      TN; vmcnt(10) drains exactly this tile's 6 loads; BAR; lgkm0; MFMA.
  //  P2: reads; stage Bh1; lgkm0 BEFORE bar (regs safe vs overwrite); MFMA.
  #define ITER(CUR, DST, TN)                                                  \
    do {                                                                      \
      READ_B4(bR, CUR)                                                        \
      READ_A4(aU, 0, CUR)                                                     \
      STAGE_A(TN, DST);                                                       \
      STAGE_BH0(TN, DST);                                                     \
      VM10                                                                    \
      BAR                                                                     \
      LGKM0                                                                   \
      MFMA16(0, aU, bR)                                                       \
      READ_A4(aV, 4, CUR)                                                     \
      STAGE_BH1(TN, DST);                                                     \
      LGKM0                                                                   \
      BAR                                                                     \
      MFMA16(4, aV, bR)                                                       \
    } while (0)

  // prologue: stage tiles 0,1 into sets 0,1 (FIFO order = gate drain order)
  STAGE_A(0, 0);
  STAGE_BH0(0, 0);
  STAGE_BH1(0, 0);
  STAGE_A(1, 24576);
  STAGE_BH0(1, 24576);
  STAGE_BH1(1, 24576);

  // 30 tiles in unroll-by-3 (set = t%3, dest = (t+2)%3), then 2-tile tail
  #pragma unroll 1
  for (int kt = 0; kt < 30; kt += 3) {
    ITER(0,     49152, kt + 2);
    ITER(24576, 0,     kt + 3);
    ITER(49152, 24576, kt + 4);
  }
  ITER(0,     49152, 31);   // t=30 (benign re-stage of tile 31 into unused set)
  ITER(24576, 0,     31);   // t=31 (benign re-stage)

  // ---- fused masked reduction (C/D layout shape-determined) ----
  // acc[m][n][r] = Gq[bi*128 + m*16 + g*4 + r][bj*256 + w*64 + n*16 + laneq]
  int tcol[4];
  float tcr[4];
  #pragma unroll
  for (int n = 0; n < 4; n++) {
    int idx = bj * BNJ + w * 64 + n * 16 + laneq;
    tcol[n] = tgt[idx];
    tcr[n] = recip[idx];
  }
  int rbase = bi * BMI + g * 4;

  #pragma unroll
  for (int m = 0; m < 8; m++) {
    #pragma unroll
    for (int r = 0; r < 4; r++) {
      int grow = rbase + m * 16 + r;
      int trow = tgt[grow];
      float rrw = recip[grow];
      float ap = -__builtin_inff(), an = __builtin_inff();
      #pragma unroll
      for (int n = 0; n < 4; n++) {
        float d = -(float)acc[m][n][r] * rrw * tcr[n];
        bool same = (trow == tcol[n]);
        ap = same ? fmaxf(ap, d) : ap;
        an = same ? an : fminf(an, d);
      }
      #pragma unroll
      for (int s = 1; s < 16; s <<= 1) {
        ap = fmaxf(ap, __shfl_xor(ap, s));
        an = fminf(an, __shfl_xor(an, s));
      }
      if (laneq == 0) {
        atomicMaxF(&dap[grow], ap);
        atomicMinF(&dan[grow], an);
      }
    }
  }
  #undef STAGE_A
  #undef STAGE_BH0
  #undef STAGE_BH1
  #undef READ_A4
  #undef READ_B4
  #undef MFMA16
  #undef SB
  #undef LGKM0
  #undef VM10
  #undef BAR
  #undef ITER
}

// ---------------- final loss ----------------
__global__ __launch_bounds__(256) void loss_kernel(const float* __restrict__ dap,
                                                   const float* __restrict__ dan,
                                                   float* __restrict__ out) {
  int t = threadIdx.x;
  float s = 0.f;
  for (int i = t; i < NROWS; i += 256) {
    float v = dap[i] - dan[i] + MARGIN_F;
    s += v > 0.f ? v : 0.f;
  }
  #pragma unroll
  for (int sh = 1; sh < 64; sh <<= 1) s += __shfl_xor(s, sh);
  __shared__ float ws[4];
  if ((t & 63) == 0) ws[t >> 6] = s;
  __syncthreads();
  if (t == 0) out[0] = (ws[0] + ws[1] + ws[2] + ws[3]) * (1.0f / (float)NROWS);
}

extern "C" void kernel_launch(void* const* d_in, const int* in_sizes, int n_in,
                              void* d_out, int out_size, void* d_ws, size_t ws_size,
                              hipStream_t stream) {
  const float* inputs = (const float*)d_in[0];
  const int* targets = (const int*)d_in[1];
  char* l2q = (char*)d_ws;
  float* recip = (float*)((char*)d_ws + (size_t)NROWS * DIMS);
  float* dap = recip + NROWS;
  float* dan = dap + NROWS;
  float* out = (float*)d_out;

  hipLaunchKernelGGL(norm_kernel, dim3(NROWS), dim3(256), 0, stream,
                     inputs, l2q, recip, dap, dan);
  hipLaunchKernelGGL(gemm_reduce_kernel, dim3(NTBI * NTBJ), dim3(256), 0, stream,
                     l2q, targets, recip, dap, dan);
  hipLaunchKernelGGL(loss_kernel, dim3(1), dim3(256), 0, stream, dap, dan, out);
}

// Round 12
// 71.506 us; speedup vs baseline: 1.0448x; 1.0448x over previous
//
#include <hip/hip_runtime.h>
#include <hip/hip_bf16.h>
#include <stdint.h>

#define NROWS 4096
#define DIMS  2048
#define BM    256
#define BKB   64              // K-tile = 64 int8 = 64 B rows
#define NTILES (DIMS / BKB)   // 32
#define NTB   (NROWS / BM)    // 16 -> 256 blocks
#define MARGIN_F 0.3f

typedef __attribute__((ext_vector_type(4))) int   i32x4;
typedef __attribute__((ext_vector_type(4))) float f32x4;

__device__ inline void atomicMaxF(float* addr, float v) {
  if (v >= 0.f) atomicMax((int*)addr, __float_as_int(v));
  else          atomicMin((unsigned int*)addr, __float_as_uint(v));
}
__device__ inline void atomicMinF(float* addr, float v) {
  if (v >= 0.f) atomicMin((int*)addr, __float_as_int(v));
  else          atomicMax((unsigned int*)addr, __float_as_uint(v));
}

__device__ inline void load_lds16(const void* g, void* l) {
  __builtin_amdgcn_global_load_lds(
      (const __attribute__((address_space(1))) void*)(g),
      (__attribute__((address_space(3))) void*)(l), 16, 0, 0);
}

// ------- normalize + per-row int8 quantization (q = rint(x*127/amax)) -------
__global__ __launch_bounds__(256) void norm_kernel(const float* __restrict__ in,
                                                   char* __restrict__ l2q,
                                                   float* __restrict__ recip,
                                                   float* __restrict__ dap,
                                                   float* __restrict__ dan) {
  int row = blockIdx.x;
  int t = threadIdx.x;
  const float4* rin = (const float4*)(in + (size_t)row * DIMS);
  float4 v0 = rin[t];
  float4 v1 = rin[t + 256];
  float ss = v0.x*v0.x + v0.y*v0.y + v0.z*v0.z + v0.w*v0.w
           + v1.x*v1.x + v1.y*v1.y + v1.z*v1.z + v1.w*v1.w;
  float am = fmaxf(fmaxf(fmaxf(fabsf(v0.x), fabsf(v0.y)), fmaxf(fabsf(v0.z), fabsf(v0.w))),
                   fmaxf(fmaxf(fabsf(v1.x), fabsf(v1.y)), fmaxf(fabsf(v1.z), fabsf(v1.w))));
  #pragma unroll
  for (int s = 1; s < 64; s <<= 1) {
    ss += __shfl_xor(ss, s);
    am = fmaxf(am, __shfl_xor(am, s));
  }
  __shared__ float wsum[4], wmax[4];
  if ((t & 63) == 0) { wsum[t >> 6] = ss; wmax[t >> 6] = am; }
  __syncthreads();
  float tot = wsum[0] + wsum[1] + wsum[2] + wsum[3];
  float amax = fmaxf(fmaxf(wmax[0], wmax[1]), fmaxf(wmax[2], wmax[3]));
  float rn = 1.0f / sqrtf(tot);
  float qs = 127.0f / amax;
  int q0 = (int)rintf(v0.x * qs), q1 = (int)rintf(v0.y * qs);
  int q2 = (int)rintf(v0.z * qs), q3 = (int)rintf(v0.w * qs);
  int q4 = (int)rintf(v1.x * qs), q5 = (int)rintf(v1.y * qs);
  int q6 = (int)rintf(v1.z * qs), q7 = (int)rintf(v1.w * qs);
  int p0 = (q0 & 255) | ((q1 & 255) << 8) | ((q2 & 255) << 16) | (q3 << 24);
  int p1 = (q4 & 255) | ((q5 & 255) << 8) | ((q6 & 255) << 16) | (q7 << 24);
  int* orow = (int*)(l2q + (size_t)row * DIMS);
  orow[t] = p0;
  orow[t + 256] = p1;
  if (t == 0) {
    recip[row] = amax * rn / 127.0f;
    dap[row] = -__builtin_inff();
    dan[row] = __builtin_inff();
  }
}

// ---------------- fused int8 GEMM (acc = Q . Q^T) + masked row max/min ----------------
// 256x256 tile, 8 waves (2M x 4N, wave tile 128x64), BK=64 int8,
// mfma_i32_16x16x64_i8 (32 MFMA/wave/K-tile).
// ONE barrier per K-tile; interior is compiler-scheduled (no lgkm pinning,
// no intra-tile barriers): waves drift out of lockstep so one wave's
// ds_reads run under another's MFMAs (the r5-r11 lockstep flooded the LDS
// port after every barrier then idled it during MFMA -- reads ~2260 cy and
// MFMA ~2610 cy per CU per 128B-K never overlapped). setprio(1) on MFMA
// clusters gives drifted MFMA-ready waves pipe priority (T5 role-split).
// LDS: 3 sets x (A 16KB + B 16KB) = 96 KB; stage tile t+2 right after the
// gate; vmcnt(6) counted gate waits tile t's 6 loads (issued 2 tiles ago),
// never a cold drain. Set-reuse hazard closed by the single barrier: all
// waves' t-1 interiors (reads consumed into regs) precede barrier arrival.
// Layout/addressing byte-identical to r9 (verified: 0 conflicts, absmax 0).
__global__ __launch_bounds__(512) void gemm_reduce_kernel(
    const char* __restrict__ l2q, const int* __restrict__ tgt,
    const float* __restrict__ recip,
    float* __restrict__ dap, float* __restrict__ dan) {
  __shared__ __attribute__((aligned(16))) char ldsbuf[98304];  // 3 x (16K A + 16K B)

  // XCD-chunked bijective swizzle (256 blocks, 8 XCDs -> 32 contiguous per XCD)
  int c = blockIdx.x;
  int swz = (c & 7) * 32 + (c >> 3);
  int bi = swz >> 4, bj = swz & 15;

  int tid = threadIdx.x;
  int lane = tid & 63, w = tid >> 6;
  int wr = w >> 2;        // 0..1  (M half: 128 rows)
  int nc = w & 3;         // 0..3  (N quarter: 64 cols)

  i32x4 acc[8][4];
  #pragma unroll
  for (int m = 0; m < 8; m++)
    #pragma unroll
    for (int n = 0; n < 4; n++) acc[m][n] = (i32x4){0, 0, 0, 0};

  // --- staging source (r9-identical): row = tid>>2 (+128 for 2nd inst),
  //     data chunk q = (tid&3) ^ ((row>>1)&3); 64B-contiguous per 4 threads ---
  int srow = tid >> 2;                               // 0..127
  int qq = (tid & 3) ^ ((tid >> 3) & 3);
  const char* gA = l2q + ((size_t)(bi * BM + srow)) * DIMS + qq * 16;
  const char* gB = l2q + ((size_t)(bj * BM + srow)) * DIMS + qq * 16;

  // --- fragment read offsets (bytes; r9-identical zero-conflict swizzle) ---
  int laneq = lane & 15, g = lane >> 4;
  int fcB = (g ^ ((laneq >> 1) & 3)) * 16;           // swizzled 16B chunk slot
  int aOffB = (wr * 128 + laneq) * 64 + fcB;
  int bOffB = 16384 + (nc * 64 + laneq) * 64 + fcB;

  i32x4 aU[4], aV[4], bR[4];

  #define STAGE_A(T, DOFF)                                                    \
    do {                                                                      \
      load_lds16(gA + (size_t)(T) * 64, &ldsbuf[(DOFF) + w * 1024]);          \
      load_lds16(gA + (size_t)128 * DIMS + (size_t)(T) * 64,                  \
                 &ldsbuf[(DOFF) + 8192 + w * 1024]);                          \
    } while (0)
  #define STAGE_B(T, DOFF)                                                    \
    do {                                                                      \
      load_lds16(gB + (size_t)(T) * 64, &ldsbuf[(DOFF) + 16384 + w * 1024]);  \
      load_lds16(gB + (size_t)128 * DIMS + (size_t)(T) * 64,                  \
                 &ldsbuf[(DOFF) + 24576 + w * 1024]);                         \
    } while (0)

  #define READ_A4(DST, MB, COFF)                                              \
    _Pragma("unroll")                                                         \
    for (int m = 0; m < 4; m++)                                               \
      DST[m] = *(const i32x4*)&ldsbuf[(COFF) + aOffB + ((MB) + m) * 1024];
  #define READ_B4(DST, COFF)                                                  \
    _Pragma("unroll")                                                         \
    for (int n = 0; n < 4; n++)                                               \
      DST[n] = *(const i32x4*)&ldsbuf[(COFF) + bOffB + n * 1024];

  #define MFMA16(MB, AR, BR)                                                  \
    __builtin_amdgcn_s_setprio(1);                                            \
    _Pragma("unroll")                                                         \
    for (int m = 0; m < 4; m++)                                               \
      _Pragma("unroll")                                                       \
      for (int n = 0; n < 4; n++)                                             \
        acc[(MB) + m][n] = __builtin_amdgcn_mfma_i32_16x16x64_i8(             \
            AR[m], BR[n], acc[(MB) + m][n], 0, 0, 0);                         \
    __builtin_amdgcn_s_setprio(0);

  #define SB __builtin_amdgcn_sched_barrier(0);

  // Tile interior: reads + MFMA, compiler-scheduled (counted lgkmcnt, intra-
  // wave read/MFMA interleave allowed).
  #define TILE_BODY(CUR)                                                      \
    do {                                                                      \
      READ_B4(bR, CUR)                                                        \
      READ_A4(aU, 0, CUR)                                                     \
      MFMA16(0, aU, bR)                                                       \
      READ_A4(aV, 4, CUR)                                                     \
      MFMA16(4, aV, bR)                                                       \
    } while (0)

  // prologue: stage tiles 0,1 into sets 0,1 (FIFO order = gate drain order)
  STAGE_A(0, 0);
  STAGE_B(0, 0);
  STAGE_A(1, 32768);
  STAGE_B(1, 32768);

  // steady state: tiles 0..29, one gate+barrier per tile, stage t+2.
  int curOff = 0, dstOff = 65536;
  #pragma unroll 1
  for (int kt = 0; kt < NTILES - 2; ++kt) {
    asm volatile("s_waitcnt vmcnt(6)" ::: "memory");   // tile kt's 6 loads done
    SB
    __builtin_amdgcn_s_barrier();                      // publish; close set reuse
    SB
    STAGE_A(kt + 2, dstOff);
    STAGE_B(kt + 2, dstOff);
    TILE_BODY(curOff);
    curOff = (curOff == 65536) ? 0 : curOff + 32768;
    dstOff = (dstOff == 65536) ? 0 : dstOff + 32768;
  }
  // tile 30: no staging, counted gate
  asm volatile("s_waitcnt vmcnt(6)" ::: "memory");
  SB
  __builtin_amdgcn_s_barrier();
  SB
  TILE_BODY(curOff);
  curOff = (curOff == 65536) ? 0 : curOff + 32768;
  // tile 31: drain (loads issued 2 tiles ago -> free)
  asm volatile("s_waitcnt vmcnt(0)" ::: "memory");
  SB
  __builtin_amdgcn_s_barrier();
  SB
  TILE_BODY(curOff);

  // ---- fused masked reduction (r9-identical) ----
  // acc[m][n][r] = Gq[bi*256 + wr*128 + m*16 + g*4 + r]
  //                  [bj*256 + nc*64  + n*16 + laneq]
  int tcol[4];
  float tcr[4];
  #pragma unroll
  for (int n = 0; n < 4; n++) {
    int idx = bj * BM + nc * 64 + n * 16 + laneq;
    tcol[n] = tgt[idx];
    tcr[n] = recip[idx];
  }
  int rbase = bi * BM + wr * 128 + g * 4;

  #pragma unroll
  for (int m = 0; m < 8; m++) {
    #pragma unroll
    for (int r = 0; r < 4; r++) {
      int grow = rbase + m * 16 + r;
      int trow = tgt[grow];
      float rrw = recip[grow];
      float ap = -__builtin_inff(), an = __builtin_inff();
      #pragma unroll
      for (int n = 0; n < 4; n++) {
        float d = -(float)acc[m][n][r] * rrw * tcr[n];
        bool same = (trow == tcol[n]);
        ap = same ? fmaxf(ap, d) : ap;
        an = same ? an : fminf(an, d);
      }
      #pragma unroll
      for (int s = 1; s < 16; s <<= 1) {
        ap = fmaxf(ap, __shfl_xor(ap, s));
        an = fminf(an, __shfl_xor(an, s));
      }
      if (laneq == 0) {
        atomicMaxF(&dap[grow], ap);
        atomicMinF(&dan[grow], an);
      }
    }
  }
  #undef STAGE_A
  #undef STAGE_B
  #undef READ_A4
  #undef READ_B4
  #undef MFMA16
  #undef SB
  #undef TILE_BODY
}

// ---------------- final loss ----------------
__global__ __launch_bounds__(256) void loss_kernel(const float* __restrict__ dap,
                                                   const float* __restrict__ dan,
                                                   float* __restrict__ out) {
  int t = threadIdx.x;
  float s = 0.f;
  for (int i = t; i < NROWS; i += 256) {
    float v = dap[i] - dan[i] + MARGIN_F;
    s += v > 0.f ? v : 0.f;
  }
  #pragma unroll
  for (int sh = 1; sh < 64; sh <<= 1) s += __shfl_xor(s, sh);
  __shared__ float ws[4];
  if ((t & 63) == 0) ws[t >> 6] = s;
  __syncthreads();
  if (t == 0) out[0] = (ws[0] + ws[1] + ws[2] + ws[3]) * (1.0f / (float)NROWS);
}

extern "C" void kernel_launch(void* const* d_in, const int* in_sizes, int n_in,
                              void* d_out, int out_size, void* d_ws, size_t ws_size,
                              hipStream_t stream) {
  const float* inputs = (const float*)d_in[0];
  const int* targets = (const int*)d_in[1];
  char* l2q = (char*)d_ws;
  float* recip = (float*)((char*)d_ws + (size_t)NROWS * DIMS);
  float* dap = recip + NROWS;
  float* dan = dap + NROWS;
  float* out = (float*)d_out;

  hipLaunchKernelGGL(norm_kernel, dim3(NROWS), dim3(256), 0, stream,
                     inputs, l2q, recip, dap, dan);
  hipLaunchKernelGGL(gemm_reduce_kernel, dim3(NTB * NTB), dim3(512), 0, stream,
                     l2q, targets, recip, dap, dan);
  hipLaunchKernelGGL(loss_kernel, dim3(1), dim3(256), 0, stream, dap, dan, out);
}

// Round 13
// 71.269 us; speedup vs baseline: 1.0483x; 1.0033x over previous
//
#include <hip/hip_runtime.h>
#include <hip/hip_bf16.h>
#include <stdint.h>

#define NROWS 4096
#define DIMS  2048
#define BM    256
#define BKB   64              // K-tile = 64 int8 = 64 B rows
#define NTILES (DIMS / BKB)   // 32
#define MARGIN_F 0.3f

typedef __attribute__((ext_vector_type(4))) int   i32x4;
typedef __attribute__((ext_vector_type(4))) float f32x4;

__device__ inline void atomicMaxF(float* addr, float v) {
  if (v >= 0.f) atomicMax((int*)addr, __float_as_int(v));
  else          atomicMin((unsigned int*)addr, __float_as_uint(v));
}
__device__ inline void atomicMinF(float* addr, float v) {
  if (v >= 0.f) atomicMin((int*)addr, __float_as_int(v));
  else          atomicMax((unsigned int*)addr, __float_as_uint(v));
}

__device__ inline void load_lds16(const void* g, void* l) {
  __builtin_amdgcn_global_load_lds(
      (const __attribute__((address_space(1))) void*)(g),
      (__attribute__((address_space(3))) void*)(l), 16, 0, 0);
}

// ------- normalize + per-row int8 quantization (q = rint(x*127/amax)) -------
__global__ __launch_bounds__(256) void norm_kernel(const float* __restrict__ in,
                                                   char* __restrict__ l2q,
                                                   float* __restrict__ recip,
                                                   float* __restrict__ dap,
                                                   float* __restrict__ dan) {
  int row = blockIdx.x;
  int t = threadIdx.x;
  const float4* rin = (const float4*)(in + (size_t)row * DIMS);
  float4 v0 = rin[t];
  float4 v1 = rin[t + 256];
  float ss = v0.x*v0.x + v0.y*v0.y + v0.z*v0.z + v0.w*v0.w
           + v1.x*v1.x + v1.y*v1.y + v1.z*v1.z + v1.w*v1.w;
  float am = fmaxf(fmaxf(fmaxf(fabsf(v0.x), fabsf(v0.y)), fmaxf(fabsf(v0.z), fabsf(v0.w))),
                   fmaxf(fmaxf(fabsf(v1.x), fabsf(v1.y)), fmaxf(fabsf(v1.z), fabsf(v1.w))));
  #pragma unroll
  for (int s = 1; s < 64; s <<= 1) {
    ss += __shfl_xor(ss, s);
    am = fmaxf(am, __shfl_xor(am, s));
  }
  __shared__ float wsum[4], wmax[4];
  if ((t & 63) == 0) { wsum[t >> 6] = ss; wmax[t >> 6] = am; }
  __syncthreads();
  float tot = wsum[0] + wsum[1] + wsum[2] + wsum[3];
  float amax = fmaxf(fmaxf(wmax[0], wmax[1]), fmaxf(wmax[2], wmax[3]));
  float rn = 1.0f / sqrtf(tot);
  float qs = 127.0f / amax;
  int q0 = (int)rintf(v0.x * qs), q1 = (int)rintf(v0.y * qs);
  int q2 = (int)rintf(v0.z * qs), q3 = (int)rintf(v0.w * qs);
  int q4 = (int)rintf(v1.x * qs), q5 = (int)rintf(v1.y * qs);
  int q6 = (int)rintf(v1.z * qs), q7 = (int)rintf(v1.w * qs);
  int p0 = (q0 & 255) | ((q1 & 255) << 8) | ((q2 & 255) << 16) | (q3 << 24);
  int p1 = (q4 & 255) | ((q5 & 255) << 8) | ((q6 & 255) << 16) | (q7 << 24);
  int* orow = (int*)(l2q + (size_t)row * DIMS);
  orow[t] = p0;
  orow[t + 256] = p1;
  if (t == 0) {
    recip[row] = amax * rn / 127.0f;
    dap[row] = -__builtin_inff();
    dan[row] = __builtin_inff();
  }
}

// ---------------- fused symmetric int8 GEMM + masked row/col max/min ----------------
// Upper-triangular 256x256 tiles only (bi<=bj): 136 tiles, clustered so each
// XCD's concurrent blocks touch <=8 row-panels (4 MB = per-XCD L2): XCD 0-5
// get one off-diagonal 4x4 super-block (16 tiles, 8 panels); XCD 6-7 get two
// diagonal supers (20 tiles, 8 panels). Grid 160 (k=16..19 of XCD 0-5 exit).
// Off-diag tiles contribute row-wise (bi-panel) AND col-wise (bj-panel, via
// G symmetry) masked max/min; diagonal tiles row-wise only.
// K-loop = r12 structure (8 waves, wave tile 128x64, mfma_i32_16x16x64_i8,
// 3 LDS sets, 1 barrier/tile, compiler-scheduled interior) with the gate
// corrected to vmcnt(4): prologue stages tiles 0,1 (8 loads); at tile kt the
// gate drains exactly kt's 4 loads (issued 2 tile-times earlier).
__global__ __launch_bounds__(512) void gemm_reduce_kernel(
    const char* __restrict__ l2q, const int* __restrict__ tgt,
    const float* __restrict__ recip,
    float* __restrict__ dap, float* __restrict__ dan) {
  __shared__ __attribute__((aligned(16))) char ldsbuf[98304];  // 3 x (16K A + 16K B)

  // ---- upper-tri cluster decode ----
  int c = blockIdx.x;
  int x = c & 7, k = c >> 3;          // x: cluster (1 per XCD), k: 0..19
  int bi, bj;
  if (x < 6) {
    if (k >= 16) return;              // 16-tile clusters
    int si = (x < 3) ? 0 : ((x < 5) ? 1 : 2);
    int sj = (x < 3) ? (x + 1) : ((x < 5) ? (x - 1) : 3);
    bi = si * 4 + (k >> 2);
    bj = sj * 4 + (k & 3);
  } else {
    int s = (x - 6) * 2 + (k >= 10 ? 1 : 0);   // diag super 0..3
    int t = (k >= 10) ? (k - 10) : k;          // 0..9 upper-tri of 4x4
    int ti = (t < 4) ? 0 : ((t < 7) ? 1 : ((t < 9) ? 2 : 3));
    int st = (ti == 0) ? 0 : ((ti == 1) ? 4 : ((ti == 2) ? 7 : 9));
    bi = s * 4 + ti;
    bj = s * 4 + ti + (t - st);
  }
  bool offd = (bi != bj);

  int tid = threadIdx.x;
  int lane = tid & 63, w = tid >> 6;
  int wr = w >> 2;        // 0..1  (M half: 128 rows)
  int nc = w & 3;         // 0..3  (N quarter: 64 cols)

  i32x4 acc[8][4];
  #pragma unroll
  for (int m = 0; m < 8; m++)
    #pragma unroll
    for (int n = 0; n < 4; n++) acc[m][n] = (i32x4){0, 0, 0, 0};

  // --- staging source (r9/r12-identical verified pattern) ---
  int srow = tid >> 2;                               // 0..127
  int qq = (tid & 3) ^ ((tid >> 3) & 3);
  const char* gA = l2q + ((size_t)(bi * BM + srow)) * DIMS + qq * 16;
  const char* gB = l2q + ((size_t)(bj * BM + srow)) * DIMS + qq * 16;

  // --- fragment read offsets (bytes; verified zero-conflict swizzle) ---
  int laneq = lane & 15, g = lane >> 4;
  int fcB = (g ^ ((laneq >> 1) & 3)) * 16;           // swizzled 16B chunk slot
  int aOffB = (wr * 128 + laneq) * 64 + fcB;
  int bOffB = 16384 + (nc * 64 + laneq) * 64 + fcB;

  i32x4 aU[4], aV[4], bR[4];

  #define STAGE_A(T, DOFF)                                                    \
    do {                                                                      \
      load_lds16(gA + (size_t)(T) * 64, &ldsbuf[(DOFF) + w * 1024]);          \
      load_lds16(gA + (size_t)128 * DIMS + (size_t)(T) * 64,                  \
                 &ldsbuf[(DOFF) + 8192 + w * 1024]);                          \
    } while (0)
  #define STAGE_B(T, DOFF)                                                    \
    do {                                                                      \
      load_lds16(gB + (size_t)(T) * 64, &ldsbuf[(DOFF) + 16384 + w * 1024]);  \
      load_lds16(gB + (size_t)128 * DIMS + (size_t)(T) * 64,                  \
                 &ldsbuf[(DOFF) + 24576 + w * 1024]);                         \
    } while (0)

  #define READ_A4(DST, MB, COFF)                                              \
    _Pragma("unroll")                                                         \
    for (int m = 0; m < 4; m++)                                               \
      DST[m] = *(const i32x4*)&ldsbuf[(COFF) + aOffB + ((MB) + m) * 1024];
  #define READ_B4(DST, COFF)                                                  \
    _Pragma("unroll")                                                         \
    for (int n = 0; n < 4; n++)                                               \
      DST[n] = *(const i32x4*)&ldsbuf[(COFF) + bOffB + n * 1024];

  #define MFMA16(MB, AR, BR)                                                  \
    __builtin_amdgcn_s_setprio(1);                                            \
    _Pragma("unroll")                                                         \
    for (int m = 0; m < 4; m++)                                               \
      _Pragma("unroll")                                                       \
      for (int n = 0; n < 4; n++)                                             \
        acc[(MB) + m][n] = __builtin_amdgcn_mfma_i32_16x16x64_i8(             \
            AR[m], BR[n], acc[(MB) + m][n], 0, 0, 0);                         \
    __builtin_amdgcn_s_setprio(0);

  #define SB __builtin_amdgcn_sched_barrier(0);

  #define TILE_BODY(CUR)                                                      \
    do {                                                                      \
      READ_B4(bR, CUR)                                                        \
      READ_A4(aU, 0, CUR)                                                     \
      MFMA16(0, aU, bR)                                                       \
      READ_A4(aV, 4, CUR)                                                     \
      MFMA16(4, aV, bR)                                                       \
    } while (0)

  // prologue: stage tiles 0,1 into sets 0,1 (FIFO order = gate drain order)
  STAGE_A(0, 0);
  STAGE_B(0, 0);
  STAGE_A(1, 32768);
  STAGE_B(1, 32768);

  int curOff = 0, dstOff = 65536;
  #pragma unroll 1
  for (int kt = 0; kt < NTILES - 2; ++kt) {
    asm volatile("s_waitcnt vmcnt(4)" ::: "memory");   // tile kt's 4 loads done
    SB
    __builtin_amdgcn_s_barrier();                      // publish; close set reuse
    SB
    STAGE_A(kt + 2, dstOff);
    STAGE_B(kt + 2, dstOff);
    TILE_BODY(curOff);
    curOff = (curOff == 65536) ? 0 : curOff + 32768;
    dstOff = (dstOff == 65536) ? 0 : dstOff + 32768;
  }
  // tile 30: no staging, counted gate
  asm volatile("s_waitcnt vmcnt(4)" ::: "memory");
  SB
  __builtin_amdgcn_s_barrier();
  SB
  TILE_BODY(curOff);
  curOff = (curOff == 65536) ? 0 : curOff + 32768;
  // tile 31: drain
  asm volatile("s_waitcnt vmcnt(0)" ::: "memory");
  SB
  __builtin_amdgcn_s_barrier();
  SB
  TILE_BODY(curOff);

  // ---- fused masked reduction ----
  // acc[m][n][r] = Gq[bi*256 + wr*128 + m*16 + g*4 + r]
  //                  [bj*256 + nc*64  + n*16 + laneq]
  int tcol[4];
  float tcr[4];
  #pragma unroll
  for (int n = 0; n < 4; n++) {
    int idx = bj * BM + nc * 64 + n * 16 + laneq;
    tcol[n] = tgt[idx];
    tcr[n] = recip[idx];
  }
  int rbase = bi * BM + wr * 128 + g * 4;

  float apc[4], anc[4];   // per-column partials (transposed contribution)
  #pragma unroll
  for (int n = 0; n < 4; n++) { apc[n] = -__builtin_inff(); anc[n] = __builtin_inff(); }

  #pragma unroll
  for (int m = 0; m < 8; m++) {
    #pragma unroll
    for (int r = 0; r < 4; r++) {
      int grow = rbase + m * 16 + r;
      int trow = tgt[grow];
      float rrw = recip[grow];
      float ap = -__builtin_inff(), an = __builtin_inff();
      #pragma unroll
      for (int n = 0; n < 4; n++) {
        float d = -(float)acc[m][n][r] * rrw * tcr[n];
        bool same = (trow == tcol[n]);
        ap = same ? fmaxf(ap, d) : ap;
        an = same ? an : fminf(an, d);
        apc[n] = same ? fmaxf(apc[n], d) : apc[n];
        anc[n] = same ? anc[n] : fminf(anc[n], d);
      }
      #pragma unroll
      for (int s = 1; s < 16; s <<= 1) {
        ap = fmaxf(ap, __shfl_xor(ap, s));
        an = fminf(an, __shfl_xor(an, s));
      }
      if (laneq == 0) {
        atomicMaxF(&dap[grow], ap);
        atomicMinF(&dan[grow], an);
      }
    }
  }

  if (offd) {
    // transposed contribution: per-column max/min -> rows of bj-panel.
    // combine across the 4 lanes sharing a column (g = lane>>4 differs).
    #pragma unroll
    for (int n = 0; n < 4; n++) {
      float ap = apc[n], an = anc[n];
      ap = fmaxf(ap, __shfl_xor(ap, 16));
      ap = fmaxf(ap, __shfl_xor(ap, 32));
      an = fminf(an, __shfl_xor(an, 16));
      an = fminf(an, __shfl_xor(an, 32));
      if (g == 0) {
        int gcol = bj * BM + nc * 64 + n * 16 + laneq;
        atomicMaxF(&dap[gcol], ap);
        atomicMinF(&dan[gcol], an);
      }
    }
  }
  #undef STAGE_A
  #undef STAGE_B
  #undef READ_A4
  #undef READ_B4
  #undef MFMA16
  #undef SB
  #undef TILE_BODY
}

// ---------------- final loss ----------------
__global__ __launch_bounds__(256) void loss_kernel(const float* __restrict__ dap,
                                                   const float* __restrict__ dan,
                                                   float* __restrict__ out) {
  int t = threadIdx.x;
  float s = 0.f;
  for (int i = t; i < NROWS; i += 256) {
    float v = dap[i] - dan[i] + MARGIN_F;
    s += v > 0.f ? v : 0.f;
  }
  #pragma unroll
  for (int sh = 1; sh < 64; sh <<= 1) s += __shfl_xor(s, sh);
  __shared__ float ws[4];
  if ((t & 63) == 0) ws[t >> 6] = s;
  __syncthreads();
  if (t == 0) out[0] = (ws[0] + ws[1] + ws[2] + ws[3]) * (1.0f / (float)NROWS);
}

extern "C" void kernel_launch(void* const* d_in, const int* in_sizes, int n_in,
                              void* d_out, int out_size, void* d_ws, size_t ws_size,
                              hipStream_t stream) {
  const float* inputs = (const float*)d_in[0];
  const int* targets = (const int*)d_in[1];
  char* l2q = (char*)d_ws;
  float* recip = (float*)((char*)d_ws + (size_t)NROWS * DIMS);
  float* dap = recip + NROWS;
  float* dan = dap + NROWS;
  float* out = (float*)d_out;

  hipLaunchKernelGGL(norm_kernel, dim3(NROWS), dim3(256), 0, stream,
                     inputs, l2q, recip, dap, dan);
  hipLaunchKernelGGL(gemm_reduce_kernel, dim3(160), dim3(512), 0, stream,
                     l2q, targets, recip, dap, dan);
  hipLaunchKernelGGL(loss_kernel, dim3(1), dim3(256), 0, stream, dap, dan, out);
}